// Round 16
// baseline (140.389 us; speedup 1.0000x reference)
//
#include <hip/hip_runtime.h>
#include <hip/hip_bf16.h>
#include <hip/hip_fp16.h>

typedef __attribute__((ext_vector_type(4))) float f32x4;
typedef __attribute__((ext_vector_type(8))) _Float16 f16x8;
typedef __attribute__((ext_vector_type(8))) unsigned short u16x8;

__device__ __forceinline__ unsigned short f2h(float f) {
    _Float16 h = (_Float16)f;
    return __builtin_bit_cast(unsigned short, h);
}

#define GLOAD_LDS16(gp, lp) __builtin_amdgcn_global_load_lds( \
    (const __attribute__((address_space(1))) void*)(gp), \
    (__attribute__((address_space(3))) void*)(lp), 16, 0, 0)
#define PRIO1() __builtin_amdgcn_s_setprio(1)
#define PRIO0() __builtin_amdgcn_s_setprio(0)
#define WAITVM(LIT) do { asm volatile("s_waitcnt vmcnt(" #LIT ")" ::: "memory"); \
                         __builtin_amdgcn_sched_barrier(0); } while (0)
// barrier WITHOUT vmcnt drain (keeps counted-vmcnt strip loads in flight)
#define BARND() do { asm volatile("s_waitcnt lgkmcnt(0)" ::: "memory"); \
                     __builtin_amdgcn_sched_barrier(0); \
                     __builtin_amdgcn_s_barrier(); \
                     __builtin_amdgcn_sched_barrier(0); } while (0)

// ---------------- fp32 -> fp16 elementwise convert ----------------
__global__ void cvt_kernel(const float* __restrict__ in, ushort* __restrict__ out, int n4) {
    int stride = gridDim.x * blockDim.x;
    for (int i = blockIdx.x * blockDim.x + threadIdx.x; i < n4; i += stride) {
        float4 v = ((const float4*)in)[i];
        ushort4 o;
        o.x = f2h(v.x); o.y = f2h(v.y); o.z = f2h(v.z); o.w = f2h(v.w);
        ((ushort4*)out)[i] = o;
    }
}

// ---------------- transpose+convert: z=0 Wk, z=1 Wv (R=768) -> WkvT; z=2 Wo (R=640) -> WoT ----------------
__global__ void transpose_cvt3(const float* __restrict__ Wk, const float* __restrict__ Wv,
                               const float* __restrict__ Wo,
                               ushort* __restrict__ WkvT, ushort* __restrict__ WoT) {
    __shared__ float tile[32][33];
    const int z = blockIdx.z;
    const float* src; ushort* dst; int R;
    const int C = 640;
    if (z == 0)      { src = Wk; dst = WkvT; R = 768; }
    else if (z == 1) { src = Wv; dst = WkvT + (size_t)640 * 768; R = 768; }
    else             { src = Wo; dst = WoT; R = 640; }
    if (blockIdx.y * 32 >= (unsigned)R) return;
    int tx = threadIdx.x, ty = threadIdx.y;
    int c = blockIdx.x * 32 + tx;
    int r0 = blockIdx.y * 32;
#pragma unroll
    for (int i = ty; i < 32; i += 8) {
        int r = r0 + i;
        tile[i][tx] = (r < R && c < C) ? src[(size_t)r * C + c] : 0.f;
    }
    __syncthreads();
    int rr = r0 + tx;
    int c0 = blockIdx.x * 32;
#pragma unroll
    for (int i = ty; i < 32; i += 8) {
        int cc = c0 + i;
        if (cc < C && rr < R) dst[(size_t)cc * R + rr] = f2h(tile[tx][i]);
    }
}

// ---------------- 128x128 GEMM (KV projection) ----------------
template<int OUT_F16, int HAS_BIAS>
__global__ __launch_bounds__(256) void gemm_bt(
    const ushort* __restrict__ A, const ushort* __restrict__ Bt,
    void* __restrict__ C, const float* __restrict__ bias,
    int M, int N, int K)
{
    __shared__ ushort As[128 * 64];
    __shared__ ushort Bs[128 * 64];
    const int tid = threadIdx.x;
    const int lane = tid & 63;
    const int w = tid >> 6;
    const int wr = (w >> 1) * 64, wc = (w & 1) * 64;
    const int m0 = blockIdx.x * 128, n0 = blockIdx.y * 128;
    const int l15 = lane & 15, lhi = lane >> 4;

    f32x4 acc[4][4] = {};

    for (int k0 = 0; k0 < K; k0 += 64) {
        __syncthreads();
#pragma unroll
        for (int i = 0; i < 4; ++i) {
            int c = i * 256 + tid;
            int m = m0 + (c >> 3);
            if (m > M - 1) m = M - 1;
            GLOAD_LDS16(A + (size_t)m * K + k0 + (c & 7) * 8, &As[c * 8]);
        }
#pragma unroll
        for (int i = 0; i < 4; ++i) {
            int c = i * 256 + tid;
            GLOAD_LDS16(Bt + (size_t)(n0 + (c >> 3)) * K + k0 + (c & 7) * 8, &Bs[c * 8]);
        }
        __syncthreads();
#pragma unroll
        for (int kk = 0; kk < 2; ++kk) {
            f16x8 af[4], bfr[4];
#pragma unroll
            for (int mi = 0; mi < 4; ++mi)
                af[mi] = *(const f16x8*)&As[(wr + mi * 16 + l15) * 64 + kk * 32 + lhi * 8];
#pragma unroll
            for (int ni = 0; ni < 4; ++ni)
                bfr[ni] = *(const f16x8*)&Bs[(wc + ni * 16 + l15) * 64 + kk * 32 + lhi * 8];
#pragma unroll
            for (int mi = 0; mi < 4; ++mi)
#pragma unroll
                for (int ni = 0; ni < 4; ++ni)
                    acc[mi][ni] = __builtin_amdgcn_mfma_f32_16x16x32_f16(
                        af[mi], bfr[ni], acc[mi][ni], 0, 0, 0);
        }
    }

#pragma unroll
    for (int mi = 0; mi < 4; ++mi)
#pragma unroll
        for (int ni = 0; ni < 4; ++ni)
#pragma unroll
            for (int r = 0; r < 4; ++r) {
                int row = m0 + wr + mi * 16 + lhi * 4 + r;
                int col = n0 + wc + ni * 16 + l15;
                if (row < M) {
                    float v = acc[mi][ni][r];
                    if (HAS_BIAS) v += bias[col];
                    if (OUT_F16) ((ushort*)C)[(size_t)row * N + col] = f2h(v);
                    else         ((float*)C)[(size_t)row * N + col] = v;
                }
            }
}

// ---------------- fold WK[b][c][h*80+s] = sum_d Wq[c][h*80+d] * K[b][s][h*80+d] ----------------
// block (h = x, b = y). s in [77,80) -> 0 (B rows zeroed). Output plain f16 [640][640] per b.
__global__ __launch_bounds__(512) void fold_wk(
    const float* __restrict__ Wq, const ushort* __restrict__ KVb, ushort* __restrict__ WKp)
{
    __shared__ ushort Al[640 * 88];   // [c][d pad]
    __shared__ ushort Bl[80 * 88];    // [s][d pad]
    const int tid = threadIdx.x, lane = tid & 63, w = tid >> 6;
    const int l15 = lane & 15, lhi = lane >> 4;
    const int h = blockIdx.x, b = blockIdx.y;
    for (int i = tid; i < 6400; i += 512) {
        int c = i / 10, oc = i % 10;
        const float* p = Wq + (size_t)c * 640 + h * 80 + oc * 8;
        u16x8 o;
#pragma unroll
        for (int e = 0; e < 8; ++e) o[e] = f2h(p[e]);
        *(u16x8*)&Al[c * 88 + oc * 8] = o;
    }
    for (int i = tid; i < 800; i += 512) {
        int s = i / 10, oc = i % 10;
        u16x8 o = {};
        if (s < 77) {
            const ushort* p = KVb + ((size_t)b * 77 + s) * 1280 + h * 80 + oc * 8;
#pragma unroll
            for (int e = 0; e < 8; ++e) o[e] = p[e];
        }
        *(u16x8*)&Bl[s * 88 + oc * 8] = o;
    }
    __syncthreads();
    const int wb = w * 80;
    f32x4 acc[5][5] = {};
    const f16x8 zf = {};
#pragma unroll
    for (int kk = 0; kk < 3; ++kk) {
        const int kcol = (kk < 2) ? (kk * 32 + lhi * 8) : (64 + (lhi & 1) * 8);
        f16x8 bf[5];
#pragma unroll
        for (int ni = 0; ni < 5; ++ni)
            bf[ni] = *(const f16x8*)&Bl[(ni * 16 + l15) * 88 + kcol];
#pragma unroll
        for (int mi = 0; mi < 5; ++mi) {
            f16x8 af = *(const f16x8*)&Al[(wb + mi * 16 + l15) * 88 + kcol];
            if (kk == 2 && lhi >= 2) af = zf;   // kill duplicated k-slots
#pragma unroll
            for (int ni = 0; ni < 5; ++ni)
                acc[mi][ni] = __builtin_amdgcn_mfma_f32_16x16x32_f16(af, bf[ni], acc[mi][ni], 0, 0, 0);
        }
    }
    ushort* dst = WKp + (size_t)b * 409600 + h * 80;
#pragma unroll
    for (int mi = 0; mi < 5; ++mi)
#pragma unroll
        for (int ni = 0; ni < 5; ++ni)
#pragma unroll
            for (int r = 0; r < 4; ++r) {
                int c = wb + mi * 16 + lhi * 4 + r;
                int s = ni * 16 + l15;
                dst[(size_t)c * 640 + s] = f2h(acc[mi][ni][r]);
            }
}

// ---------------- fold VW[b][h*80+s][n] = sum_d V[b][s][h*80+d] * Wo[h*80+d][n] ----------------
// block (h = x, b = y). A = V staged (s>=77 zero rows); B-frags gathered from WoT[n][hd].
__global__ __launch_bounds__(512) void fold_vw(
    const ushort* __restrict__ KVb, const ushort* __restrict__ WoT, ushort* __restrict__ VWp)
{
    __shared__ ushort Al[80 * 88];
    const int tid = threadIdx.x, lane = tid & 63, w = tid >> 6;
    const int l15 = lane & 15, lhi = lane >> 4;
    const int h = blockIdx.x, b = blockIdx.y;
    for (int i = tid; i < 800; i += 512) {
        int s = i / 10, oc = i % 10;
        u16x8 o = {};
        if (s < 77) {
            const ushort* p = KVb + ((size_t)b * 77 + s) * 1280 + 640 + h * 80 + oc * 8;
#pragma unroll
            for (int e = 0; e < 8; ++e) o[e] = p[e];
        }
        *(u16x8*)&Al[s * 88 + oc * 8] = o;
    }
    __syncthreads();
    const int nb = w * 80;
    f32x4 acc[5][5] = {};
    const f16x8 zf = {};
#pragma unroll
    for (int kk = 0; kk < 3; ++kk) {
        const int kcol = (kk < 2) ? (kk * 32 + lhi * 8) : (64 + (lhi & 1) * 8);
        f16x8 af[5];
#pragma unroll
        for (int mi = 0; mi < 5; ++mi) {
            af[mi] = *(const f16x8*)&Al[(mi * 16 + l15) * 88 + kcol];
            if (kk == 2 && lhi >= 2) af[mi] = zf;
        }
#pragma unroll
        for (int ni = 0; ni < 5; ++ni) {
            f16x8 bf = *(const f16x8*)(WoT + (size_t)(nb + ni * 16 + l15) * 640 + h * 80 + kcol);
#pragma unroll
            for (int mi = 0; mi < 5; ++mi)
                acc[mi][ni] = __builtin_amdgcn_mfma_f32_16x16x32_f16(af[mi], bf, acc[mi][ni], 0, 0, 0);
        }
    }
    ushort* dst = VWp + (size_t)b * 409600 + (size_t)(h * 80) * 640;
#pragma unroll
    for (int mi = 0; mi < 5; ++mi)
#pragma unroll
        for (int ni = 0; ni < 5; ++ni)
#pragma unroll
            for (int r = 0; r < 4; ++r) {
                int s = mi * 16 + lhi * 4 + r;       // rows 77..79 are zero (A zeroed)
                int n = nb + ni * 16 + l15;
                dst[(size_t)s * 640 + n] = f2h(acc[mi][ni][r]);
            }
}

// ---------------- pack plain [k=640][n=640] f16 -> fragment-linear (z=0 WK, z=1 VW) ----------------
__global__ void pack_f(const ushort* __restrict__ WKp, const ushort* __restrict__ VWp,
                       ushort* __restrict__ WKF, ushort* __restrict__ VWF) {
    int g = blockIdx.x * 256 + threadIdx.x;   // 0..51199 per (b,z)
    if (g >= 51200) return;
    int b = blockIdx.y;
    const ushort* src = (blockIdx.z ? VWp : WKp) + (size_t)b * 409600;
    ushort* dst = (blockIdx.z ? VWF : WKF) + (size_t)b * 409600;
    int lane = g & 63;
    int fi = (g >> 6) % 10;
    int kt = ((g >> 6) / 10) % 10;
    int sl = (g >> 6) / 100;                  // slice 0..7
    int ni = fi >> 1, kk = fi & 1;
    int n = sl * 80 + ni * 16 + (lane & 15);
    int k0 = kt * 64 + kk * 32 + (lane >> 4) * 8;
    u16x8 o;
#pragma unroll
    for (int e = 0; e < 8; ++e) o[e] = src[(size_t)(k0 + e) * 640 + n];
    *(u16x8*)&dst[(size_t)g * 8] = o;
}

// ================= fused: tokens -> scores(=QK^T via WK) -> softmax -> out(=PV·Wo via VW) =================
// R16: associativity restructure. scores = tokens @ WK[b] (K=640, one phase replaces
// Q-proj+QK^T); out = P @ VW[b] (K=640 over h*80+s, replaces PV+O-proj). Per wave:
// 800 MFMA (was 920), 2 GEMM phases (was 4), no Q round-trip, no K/V frag loads.
// Micro-structure (strips, counted vmcnt, raw barriers, swizzles) = R15 verbatim.
// XCD locality: b = blockIdx.x & 7 pins each batch's 1.6 MB WKF+VWF to one XCD L2.
// LDS: toks dbuf @0/4096; qstrips @8192+w*7680 (3 slots); P [64][640] swz @0 (alias);
//      ostrips @40960+w*5120 (2 slots, disjoint from P).
__global__ __launch_bounds__(512, 2) void fused_attn(
    const float* __restrict__ tokens, const ushort* __restrict__ WKF,
    const ushort* __restrict__ VWF, const float* __restrict__ bo,
    float* __restrict__ out)
{
    __shared__ __align__(16) ushort lds[81920];   // 160 KiB
    const int tid = threadIdx.x;
    const int lane = tid & 63;
    const int w = tid >> 6;
    const int l15 = lane & 15, lhi = lane >> 4;
    const int bid = blockIdx.x;
    const int b = bid & 7;                 // XCD-pinned batch
    const int tt = bid >> 3;
    const size_t rowbase = (size_t)b * 4096 + (size_t)tt * 64;

    const ushort* WKFb = WKF + ((size_t)b * 800 + (size_t)w * 100) * 512;
    const ushort* VWFb = VWF + ((size_t)b * 800 + (size_t)w * 100) * 512;
    const int qstrip = 8192 + w * 7680;    // 3 slots x 2560
    const int ostrip = 40960 + w * 5120;   // 2 slots x 2560

    const int srow = tid >> 3;             // 0..63
    const int sc8  = tid & 7;
    const int sphys = (sc8 ^ (srow & 7)) * 8;

#define STAGE_LOAD(C, A0, B0) do { \
    const float* p_ = tokens + (rowbase + srow) * 640 + (C) * 64 + sc8 * 8; \
    A0 = ((const float4*)p_)[0]; B0 = ((const float4*)p_)[1]; \
} while (0)
#define STAGE_WRITE(BUF, A0, B0) do { \
    u16x8 o_; \
    o_[0]=f2h(A0.x); o_[1]=f2h(A0.y); o_[2]=f2h(A0.z); o_[3]=f2h(A0.w); \
    o_[4]=f2h(B0.x); o_[5]=f2h(B0.y); o_[6]=f2h(B0.z); o_[7]=f2h(B0.w); \
    *(u16x8*)&lds[(BUF) * 4096 + srow * 64 + sphys] = o_; \
} while (0)

#define GLOADB_Q(HX) do { \
    if ((HX) <= 19) { \
        const ushort* s_ = WKFb + ((HX) >> 1) * 5120 + ((HX) & 1) * 512 + lane * 8; \
        _Pragma("unroll") for (int f_ = 0; f_ < 5; ++f_) \
            GLOAD_LDS16(s_ + f_ * 1024, &lds[qstrip + ((HX) % 3) * 2560 + f_ * 512]); \
    } \
} while (0)
#define GLOADB_O(HX) do { \
    if ((HX) <= 19) { \
        const ushort* s_ = VWFb + ((HX) >> 1) * 5120 + ((HX) & 1) * 512 + lane * 8; \
        _Pragma("unroll") for (int f_ = 0; f_ < 5; ++f_) \
            GLOAD_LDS16(s_ + f_ * 1024, &lds[ostrip + ((HX) & 1) * 2560 + f_ * 512]); \
    } \
} while (0)

    f32x4 acc[4][5];
#define ZACC() do { \
    _Pragma("unroll") for (int i_ = 0; i_ < 4; ++i_) \
    _Pragma("unroll") for (int j_ = 0; j_ < 5; ++j_) \
        acc[i_][j_] = (f32x4){0.f, 0.f, 0.f, 0.f}; \
} while (0)

#define MFMA_Q(KT, KK) do { \
    f16x8 bf_[5]; \
    _Pragma("unroll") for (int ni = 0; ni < 5; ++ni) \
        bf_[ni] = *(const f16x8*)&lds[qstrip + ((2*(KT)+(KK)) % 3) * 2560 + ni * 512 + lane * 8]; \
    PRIO1(); \
    _Pragma("unroll") for (int mi = 0; mi < 4; ++mi) { \
        int row_ = mi * 16 + l15; \
        f16x8 a_ = *(const f16x8*)&lds[((KT) & 1) * 4096 + row_ * 64 + (((KK)*4 + lhi) ^ (row_ & 7)) * 8]; \
        _Pragma("unroll") for (int ni = 0; ni < 5; ++ni) \
            acc[mi][ni] = __builtin_amdgcn_mfma_f32_16x16x32_f16(a_, bf_[ni], acc[mi][ni], 0, 0, 0); \
    } \
    PRIO0(); \
} while (0)
#define MFMA_O(HX) do { \
    f16x8 bf_[5]; \
    _Pragma("unroll") for (int ni = 0; ni < 5; ++ni) \
        bf_[ni] = *(const f16x8*)&lds[ostrip + ((HX) & 1) * 2560 + ni * 512 + lane * 8]; \
    PRIO1(); \
    _Pragma("unroll") for (int mi = 0; mi < 4; ++mi) { \
        int row_ = mi * 16 + l15; \
        f16x8 a_ = *(const f16x8*)&lds[row_ * 640 + (((HX) >> 1) * 8 + ((((HX) & 1)*4 + lhi) ^ (row_ & 7))) * 8]; \
        _Pragma("unroll") for (int ni = 0; ni < 5; ++ni) \
            acc[mi][ni] = __builtin_amdgcn_mfma_f32_16x16x32_f16(a_, bf_[ni], acc[mi][ni], 0, 0, 0); \
    } \
    PRIO0(); \
} while (0)

#define QKT(KT, WA, WB, LA, LB, WRA, WRB) do { \
    if ((KT) < 8) STAGE_LOAD((KT) + 2, LA, LB); \
    GLOADB_Q(2*(KT) + 2); \
    WAITVM(WA); \
    if ((KT) < 9) STAGE_WRITE(((KT)+1) & 1, WRA, WRB); \
    MFMA_Q(KT, 0); \
    GLOADB_Q(2*(KT) + 3); \
    WAITVM(WB); \
    MFMA_Q(KT, 1); \
    BARND(); \
} while (0)

    // ---- prologue ----
    float4 sA0, sB0, sA1, sB1;
    STAGE_LOAD(0, sA0, sB0);
    STAGE_LOAD(1, sA1, sB1);
    GLOADB_Q(0);
    GLOADB_Q(1);
    WAITVM(10);
    STAGE_WRITE(0, sA0, sB0);
    BARND();

    // ---- scores = tokens @ WK[b]  (counted-vmcnt pipeline) ----
    ZACC();
    QKT(0, 10, 10, sA0, sB0, sA1, sB1);
    QKT(1, 10, 10, sA1, sB1, sA0, sB0);
    QKT(2, 10, 10, sA0, sB0, sA1, sB1);
    QKT(3, 10, 10, sA1, sB1, sA0, sB0);
    QKT(4, 10, 10, sA0, sB0, sA1, sB1);
    QKT(5, 10, 10, sA1, sB1, sA0, sB0);
    QKT(6, 10, 10, sA0, sB0, sA1, sB1);
    QKT(7, 10, 10, sA1, sB1, sA0, sB0);
    QKT(8, 10, 10, sA0, sB0, sA1, sB1);
    QKT(9,  5,  0, sA0, sB0, sA1, sB1);
#undef QKT

    // ---- softmax over s (77 valid) + write P f16 swizzled into [64][640] @0 ----
    const float sc = 0.11180339887498949f;   // 1/sqrt(80)
#pragma unroll
    for (int mi = 0; mi < 4; ++mi)
#pragma unroll
        for (int r = 0; r < 4; ++r) {
            float v0 = acc[mi][0][r]*sc, v1 = acc[mi][1][r]*sc, v2 = acc[mi][2][r]*sc,
                  v3 = acc[mi][3][r]*sc, v4 = acc[mi][4][r]*sc;
            bool ok4 = l15 < 13;             // col 64+l15 < 77
            float mx = fmaxf(fmaxf(v0, v1), fmaxf(v2, v3));
            if (ok4) mx = fmaxf(mx, v4);
#pragma unroll
            for (int off = 1; off < 16; off <<= 1) mx = fmaxf(mx, __shfl_xor(mx, off, 16));
            float p0 = __expf(v0-mx), p1 = __expf(v1-mx), p2 = __expf(v2-mx), p3 = __expf(v3-mx);
            float p4 = ok4 ? __expf(v4-mx) : 0.f;
            float sm = p0+p1+p2+p3+p4;
#pragma unroll
            for (int off = 1; off < 16; off <<= 1) sm += __shfl_xor(sm, off, 16);
            float inv = 1.f / sm;
            int row = mi*16 + lhi*4 + r;
            float pv0 = p0*inv, pv1 = p1*inv, pv2 = p2*inv, pv3 = p3*inv, pv4 = p4*inv;
            float pvs[5] = {pv0, pv1, pv2, pv3, pv4};
#pragma unroll
            for (int ni = 0; ni < 5; ++ni) {
                int col = w*80 + ni*16 + l15;
                int slot = col >> 3;
                int phys = (slot & ~7) | ((slot ^ row) & 7);
                lds[row*640 + phys*8 + (col & 7)] = f2h(pvs[ni]);
            }
        }
    BARND();                               // P ready block-wide

    // ---- out = P @ VW[b] + bo  (counted-vmcnt, 2-slot distance-1) ----
    ZACC();
    GLOADB_O(0);
#define OH(HX, W) do { GLOADB_O((HX) + 1); WAITVM(W); MFMA_O(HX); } while (0)
    OH(0, 5);  OH(1, 5);  OH(2, 5);  OH(3, 5);  OH(4, 5);
    OH(5, 5);  OH(6, 5);  OH(7, 5);  OH(8, 5);  OH(9, 5);
    OH(10, 5); OH(11, 5); OH(12, 5); OH(13, 5); OH(14, 5);
    OH(15, 5); OH(16, 5); OH(17, 5); OH(18, 5); OH(19, 0);
#undef OH

    // ---- epilogue: f32 out + bias ----
#pragma unroll
    for (int ni = 0; ni < 5; ++ni) {
        int col = w*80 + ni*16 + l15;
        float bvl = bo[col];
#pragma unroll
        for (int mi = 0; mi < 4; ++mi)
#pragma unroll
            for (int r = 0; r < 4; ++r)
                out[(rowbase + mi*16 + lhi*4 + r) * 640 + col] = acc[mi][ni][r] + bvl;
    }
#undef STAGE_LOAD
#undef STAGE_WRITE
#undef GLOADB_Q
#undef GLOADB_O
#undef MFMA_Q
#undef MFMA_O
#undef ZACC
}

extern "C" void kernel_launch(void* const* d_in, const int* in_sizes, int n_in,
                              void* d_out, int out_size, void* d_ws, size_t ws_size,
                              hipStream_t stream) {
    (void)in_sizes; (void)n_in; (void)out_size; (void)ws_size;
    const float* tokens  = (const float*)d_in[0];
    const float* context = (const float*)d_in[1];
    const float* Wq = (const float*)d_in[2];
    const float* Wk = (const float*)d_in[3];
    const float* Wv = (const float*)d_in[4];
    const float* Wo = (const float*)d_in[5];
    const float* bo = (const float*)d_in[6];
    float* out = (float*)d_out;

    ushort* ws   = (ushort*)d_ws;
    ushort* ctx16 = ws;                                   // 616*768
    ushort* WkvT = ctx16 + (size_t)616 * 768;             // 1280*768
    ushort* WoT  = WkvT + (size_t)1280 * 768;             // 640*640
    ushort* KVb  = WoT  + (size_t)640 * 640;              // 616*1280
    ushort* WKp  = KVb  + (size_t)616 * 1280;             // 8*640*640
    ushort* VWp  = WKp  + (size_t)8 * 409600;             // 8*640*640
    ushort* WKF  = VWp  + (size_t)8 * 409600;             // 8*640*640
    ushort* VWF  = WKF  + (size_t)8 * 409600;             // 8*640*640

    cvt_kernel<<<462, 256, 0, stream>>>(context, ctx16, 616 * 768 / 4);
    transpose_cvt3<<<dim3(20, 24, 3), dim3(32, 8), 0, stream>>>(Wk, Wv, Wo, WkvT, WoT);
    gemm_bt<1, 0><<<dim3(5, 10), 256, 0, stream>>>(ctx16, WkvT, KVb, nullptr, 616, 1280, 768);
    fold_wk<<<dim3(8, 8), 512, 0, stream>>>(Wq, KVb, WKp);
    fold_vw<<<dim3(8, 8), 512, 0, stream>>>(KVb, WoT, VWp);
    pack_f<<<dim3(200, 8, 2), 256, 0, stream>>>(WKp, VWp, WKF, VWF);
    fused_attn<<<512, 512, 0, stream>>>(tokens, WKF, VWF, bo, out);
}